// Round 17
// baseline (93.991 us; speedup 1.0000x reference)
//
#include <hip/hip_runtime.h>
#include <cstddef>

typedef unsigned short u16;
typedef __bf16 bf16x8 __attribute__((ext_vector_type(8)));
typedef float f32x4 __attribute__((ext_vector_type(4)));

// Problem constants
constexpr int B_   = 32;
constexpr int CTX_ = 128;
constexpr int NF_  = 128;     // frames
constexpr int NS_  = 32768;   // samples
constexpr int NE_  = 16;      // events
constexpr int CH_  = 256;
constexpr int NC_  = 257;     // coeffs
constexpr int TC_  = 514;     // 2*coeffs
constexpr int ROWS_ = B_ * NF_;  // 4096
constexpr int K3MLP_ = 768;      // 3*256 (logical triplet K)
constexpr int SEGM_ = 256;       // MLP pair-plane width
constexpr int K3IR_ = 960;       // 3*320 (logical triplet K, irfft)
constexpr int SEGI_ = 320;       // irfft pair-plane width (content 258/256 + zeros)
constexpr int PIRW_ = 2 * SEGI_; // 640 u16 per AB row
constexpr int PMLW_ = 2 * SEGM_; // 512 u16 per H/W row
constexpr float PI_ = 3.14159265358979323846f;

__device__ __forceinline__ float lrelu(float v) { return v > 0.f ? v : 0.2f * v; }
__device__ __forceinline__ u16 f2bf(float x) {
    unsigned u = __float_as_uint(x);
    return (u16)((u + 0x7FFFu + ((u >> 16) & 1u)) >> 16);
}
__device__ __forceinline__ float bf2f(u16 h) { return __uint_as_float(((unsigned)h) << 16); }

// ============ prep: table(pair,LUT) | weights(pair) | compact | U | V ============
// [0,1280): irfft pair table  [1280,2368): weight pairs
// [2368,2880): tap compaction [2880,2912): U rows  [2912,3040): V rows
__global__ __launch_bounds__(256) void prep_kernel(
    const float* __restrict__ param, const float* __restrict__ pw,
    const float* __restrict__ pb, const float* __restrict__ pos,
    const float* __restrict__ w0, const float* __restrict__ w1,
    const float* __restrict__ w2, const float* __restrict__ wo,
    const float* __restrict__ times,
    u16* __restrict__ Tt, u16* __restrict__ W1p, u16* __restrict__ W2p,
    u16* __restrict__ WOp, int* __restrict__ cnt, float2* __restrict__ taps,
    float* __restrict__ U, float* __restrict__ V)
{
    int blk = blockIdx.x;
    int tid = threadIdx.x;
    if (blk < 1280) {
        // ---- irfft pair table via 512-entry cos LUT ----
        __shared__ float lut[512];
        lut[tid]       = cosf((float)tid * (PI_ / 256.f));
        lut[tid + 256] = cosf((float)(tid + 256) * (PI_ / 256.f));
        __syncthreads();
        int idx = blk * 256 + tid;              // < 2*256*640
        int z = idx / (256 * PIRW_);
        int r = idx - z * (256 * PIRW_);
        int n = r / PIRW_, c = r - n * PIRW_;
        bool hiplane = c < SEGI_;
        int j = hiplane ? c : c - SEGI_;
        float val = 0.f;
        if (z == 0) {
            if (j < 129) {
                int k = 2 * j;
                float w = (k == 0 || k == 256) ? 1.f : 2.f;
                int m = (k * n) & 511;
                val = w * (1.f / 512.f) * lut[m];
            } else if (j < 258) {
                int kk = 2 * (j - 129);
                float w = (kk == 0 || kk == 256) ? 1.f : 2.f;
                int m = (kk * n) & 511;
                val = -w * (1.f / 512.f) * lut[(m - 128) & 511];   // sin
            }
        } else {
            if (j < 128) {
                int k = 2 * j + 1;
                int m = (k * n) & 511;
                val = 2.f * (1.f / 512.f) * lut[m];
            } else if (j < 256) {
                int kk = 2 * (j - 128) + 1;
                int m = (kk * n) & 511;
                val = -2.f * (1.f / 512.f) * lut[(m - 128) & 511]; // sin
            }
        }
        u16 h = f2bf(val);
        Tt[idx] = hiplane ? h : f2bf(val - bf2f(h));
    } else if (blk < 2368) {
        // ---- weight pairs (hi|lo planar) ----
        int row = blk - 1280;        // 0..1087
        int k = tid;
        float v;
        u16* p;
        if (row < 256) {
            v = w1[row * 256 + k];
            p = W1p + (size_t)row * PMLW_;
        } else if (row < 512) {
            v = w2[(row - 256) * 256 + k];
            p = W2p + (size_t)(row - 256) * PMLW_;
        } else {
            int n = row - 512;       // 0..575, valid < 514
            v = (n < TC_) ? wo[n * 256 + k] : 0.f;
            p = WOp + (size_t)n * PMLW_;
        }
        u16 h = f2bf(v);
        p[k] = h; p[256 + k] = f2bf(v - bf2f(h));
    } else if (blk < 2880) {
        // ---- tap compaction ----
        int be = blk - 2368;
        __shared__ int c;
        if (tid == 0) c = 0;
        __syncthreads();
        if (tid < NF_) {
            float v = times[(size_t)be * NF_ + tid];
            if (v != 0.f) {
                int slot = atomicAdd(&c, 1);
                taps[(size_t)be * NF_ + slot] = make_float2((float)tid, v);
            }
        }
        __syncthreads();
        if (tid == 0) cnt[be] = c;
    } else if (blk < 2912) {
        // ---- U rows: recompute y0[b] in LDS, then U[b][n] = y0 . w0[n] ----
        int b = blk - 2880;      // 0..31
        __shared__ float ly[256];
        {
            const float* pr = param + b * CTX_;
            const float* wr = pw + tid * CTX_;
            float s = 0.f;
            #pragma unroll 4
            for (int j = 0; j < CTX_; ++j) s += pr[j] * wr[j];
            ly[tid] = s + pb[tid];
        }
        __syncthreads();
        {
            const float* wn = w0 + tid * CH_;
            float s = 0.f;
            #pragma unroll 4
            for (int c2 = 0; c2 < CH_; ++c2) s += ly[c2] * wn[c2];
            U[b * CH_ + tid] = s;
        }
    } else {
        // ---- V rows: V[f][n] = pos[f] . w0[n] ----
        int f = blk - 2912;      // 0..127
        const float* pf = pos + f * CH_;
        const float* wn = w0 + tid * CH_;
        float s = 0.f;
        #pragma unroll 4
        for (int c2 = 0; c2 < CH_; ++c2) s += pf[c2] * wn[c2];
        V[f * CH_ + tid] = s;
    }
}

// ---------------- fuse1: H1 pair = lrelu(U[b] + V[f] + b0) ----------------
__global__ void fuse1_kernel(const float* __restrict__ U, const float* __restrict__ V,
                             const float* __restrict__ b0, u16* __restrict__ Hp) {
    int idx = blockIdx.x * 256 + threadIdx.x;   // 4096*256
    int c = idx & 255;
    int row = idx >> 8;
    int b = row >> 7, f = row & 127;
    float v = lrelu(U[b * CH_ + c] + V[f * CH_ + c] + b0[c]);
    u16 h = f2bf(v);
    u16* p = Hp + (size_t)row * PMLW_;
    p[c] = h; p[256 + c] = f2bf(v - bf2f(h));
}

// ---------------- mfgemm: C = A3 @ B3^T, bf16-split MFMA on PAIR buffers ----------
// Logical triplet A=[Ah|Al|Ah], B=[Bh|Bh|Bl] with plane width SEG; global buffers
// store only [hi|lo]; prefetch offsets remapped at compile time:
//   kA(kt) = kt>=2*SEG ? kt-2*SEG : kt ;  kB(kt) = kt>=SEG ? kt-SEG : kt.
// 32x64 tile, 128 threads, depth-2 prefetch, double-buffered LDS (24KB).
// EPI 0: bias+lrelu -> bf16 pair (ldc=512); EPI 1: bias -> fp32 (N-guarded);
// EPI 2: plain fp32 (z-batched).
template<int EPI, int K3, int SEG>
__global__ __launch_bounds__(128) void mfgemm(
    const u16* __restrict__ A3, const u16* __restrict__ B3,
    const float* __restrict__ bias, void* __restrict__ Cout,
    int N, int lda, int ldb, int ldc,
    size_t sAz, size_t sBz, size_t sCz)
{
    constexpr int NSTEP = K3 / 64;
    A3 += (size_t)blockIdx.z * sAz;
    B3 += (size_t)blockIdx.z * sBz;
    const int tid = threadIdx.x;
    const int m0 = blockIdx.y * 32, n0 = blockIdx.x * 64;
    __shared__ __align__(16) u16 Als[2 * 32 * 64];   //  8KB
    __shared__ __align__(16) u16 Bls[2 * 64 * 64];   // 16KB
    const int sr = tid >> 2;
    const int sc = (tid & 3) * 16;
    const u16* ga  = A3 + (size_t)(m0 + sr) * lda + sc;
    const u16* gb0 = B3 + (size_t)(n0 + sr) * ldb + sc;
    const u16* gb1 = B3 + (size_t)(n0 + 32 + sr) * ldb + sc;
    const int xr = (sr & 7) << 4;
    const int loA0 = sr * 128 + ((sc * 2) ^ xr);
    const int loA1 = sr * 128 + ((sc * 2 + 16) ^ xr);
    const int loB2 = (sr + 32) * 128 + ((sc * 2) ^ xr);
    const int loB3 = (sr + 32) * 128 + ((sc * 2 + 16) ^ xr);
    const int wv = tid >> 6, lane = tid & 63;
    const int wc = wv * 32;
    const int lr = lane & 15;
    const int lkb = (lane >> 4) * 16;
    const int xf = (lr & 7) << 4;
    const int raf0 = lr * 128, raf1 = (16 + lr) * 128;
    const int rbf0 = (wc + lr) * 128, rbf1 = (wc + 16 + lr) * 128;
    f32x4 acc00 = {0.f, 0.f, 0.f, 0.f}, acc01 = acc00, acc10 = acc00, acc11 = acc00;

    uint4 pa0, pa1, pb0, pb1, pb2, pb3;   // set P
    uint4 qa0, qa1, qb0, qb1, qb2, qb3;   // set Q
    auto kA = [](int kt) { return kt >= 2 * SEG ? kt - 2 * SEG : kt; };
    auto kB = [](int kt) { return kt >= SEG ? kt - SEG : kt; };
    auto loadP = [&](int kt) {
        int a = kA(kt), b = kB(kt);
        pa0 = *(const uint4*)(ga + a);  pa1 = *(const uint4*)(ga + a + 8);
        pb0 = *(const uint4*)(gb0 + b); pb1 = *(const uint4*)(gb0 + b + 8);
        pb2 = *(const uint4*)(gb1 + b); pb3 = *(const uint4*)(gb1 + b + 8);
    };
    auto loadQ = [&](int kt) {
        int a = kA(kt), b = kB(kt);
        qa0 = *(const uint4*)(ga + a);  qa1 = *(const uint4*)(ga + a + 8);
        qb0 = *(const uint4*)(gb0 + b); qb1 = *(const uint4*)(gb0 + b + 8);
        qb2 = *(const uint4*)(gb1 + b); qb3 = *(const uint4*)(gb1 + b + 8);
    };
    auto compute = [&](int p) {
        const char* pa = (const char*)Als + p * 4096;
        const char* pb = (const char*)Bls + p * 8192;
        #pragma unroll
        for (int s = 0; s < 2; ++s) {
            int kb = (s * 64 + lkb) ^ xf;
            bf16x8 a0 = *(const bf16x8*)(pa + raf0 + kb);
            bf16x8 a1 = *(const bf16x8*)(pa + raf1 + kb);
            bf16x8 b0 = *(const bf16x8*)(pb + rbf0 + kb);
            bf16x8 b1 = *(const bf16x8*)(pb + rbf1 + kb);
            acc00 = __builtin_amdgcn_mfma_f32_16x16x32_bf16(a0, b0, acc00, 0, 0, 0);
            acc01 = __builtin_amdgcn_mfma_f32_16x16x32_bf16(a0, b1, acc01, 0, 0, 0);
            acc10 = __builtin_amdgcn_mfma_f32_16x16x32_bf16(a1, b0, acc10, 0, 0, 0);
            acc11 = __builtin_amdgcn_mfma_f32_16x16x32_bf16(a1, b1, acc11, 0, 0, 0);
        }
    };
    auto stage = [&](int p, const uint4& a0, const uint4& a1, const uint4& b0,
                     const uint4& b1, const uint4& b2, const uint4& b3) {
        char* ab = (char*)Als + p * 4096;
        char* bb = (char*)Bls + p * 8192;
        *(uint4*)(ab + loA0) = a0; *(uint4*)(ab + loA1) = a1;
        *(uint4*)(bb + loA0) = b0; *(uint4*)(bb + loA1) = b1;
        *(uint4*)(bb + loB2) = b2; *(uint4*)(bb + loB3) = b3;
    };
    loadP(0);
    if (NSTEP > 1) loadQ(64);
    int p = 0;
    #pragma unroll
    for (int i = 0; i < NSTEP; ++i) {
        if ((i & 1) == 0) {
            stage(p, pa0, pa1, pb0, pb1, pb2, pb3);
            __syncthreads();
            if (i + 2 < NSTEP) loadP((i + 2) * 64);
            compute(p);
        } else {
            stage(p, qa0, qa1, qb0, qb1, qb2, qb3);
            __syncthreads();
            if (i + 2 < NSTEP) loadQ((i + 2) * 64);
            compute(p);
        }
        p ^= 1;
    }
    const int er = (lane >> 4) * 4;
    const int ec = lane & 15;
    auto emit = [&](const f32x4& A, int mi, int ni) {
        #pragma unroll
        for (int r = 0; r < 4; ++r) {
            int m = m0 + mi * 16 + er + r;
            int n = n0 + wc + ni * 16 + ec;
            float v = A[r];
            if (EPI == 0) {
                v = lrelu(v + bias[n]);
                u16 h = f2bf(v);
                u16* p2 = (u16*)Cout + (size_t)m * ldc + n;
                p2[0] = h; p2[256] = f2bf(v - bf2f(h));
            } else if (EPI == 1) {
                if (n < N) ((float*)Cout)[(size_t)m * ldc + n] = v + bias[n];
            } else {
                float* cf = (float*)Cout + (size_t)blockIdx.z * sCz;
                cf[(size_t)m * ldc + n] = v;
            }
        }
    };
    emit(acc00, 0, 0); emit(acc01, 0, 1); emit(acc10, 1, 0); emit(acc11, 1, 1);
}

// ---------------- fused scan: chunk sums + serial prefix (LDS) + sincos + pair writes --
// grid (B_, 17), block 256 = 16 k (tid&15, fast) x 16 chunks (tid>>4).
// kg<16: k = kg*16 + (tid&15). kg==16: k=256 for (tid&15)==0; other threads zero pads.
// Prefix = serial sum over chunks 0..c-1 in order -> bit-identical to two-pass scan.
__global__ __launch_bounds__(256) void scanf_kernel(
    const float* __restrict__ raw, const float* __restrict__ noise,
    u16* __restrict__ ABe, u16* __restrict__ ABo)
{
    int b = blockIdx.x;
    int kg = blockIdx.y;
    int tid = threadIdx.x;
    int kl = tid & 15;
    int chunk = tid >> 4;
    bool active;
    int k;
    if (kg < 16) { k = kg * 16 + kl; active = true; }
    else         { k = 256;          active = (kl == 0); }

    __shared__ double ss[256];
    float dj[8], mj[8];
    double s = 0.0;
    float kf = (float)k * (PI_ / 256.f);
    int f0 = chunk * 8;
    if (active) {
        #pragma unroll
        for (int j = 0; j < 8; ++j) {
            size_t row = (size_t)(b * NF_ + f0 + j);
            float2 v = *(const float2*)(raw + row * TC_ + 2 * k);
            dj[j] = (1.f + v.y * noise[row * NC_ + k]) * kf;
            mj[j] = fabsf(v.x);
            s += (double)dj[j];
        }
    }
    ss[tid] = s;
    __syncthreads();
    if (active) {
        double p = 0.0;
        for (int cc = 0; cc < chunk; ++cc)
            p += ss[cc * 16 + kl];           // serial, order-preserving prefix
        int half = k >> 1;
        bool even = (k & 1) == 0;
        int ccol = half;
        int scol = even ? (129 + half) : (128 + half);
        u16* dst = even ? ABe : ABo;
        #pragma unroll
        for (int j = 0; j < 8; ++j) {
            p += (double)dj[j];
            float sn, cs;
            sincosf((float)p, &sn, &cs);
            float a = mj[j] * cs, bb = mj[j] * sn;
            u16* pr = dst + (size_t)(b * NF_ + f0 + j) * PIRW_;
            u16 ha = f2bf(a);
            pr[ccol] = ha; pr[SEGI_ + ccol] = f2bf(a - bf2f(ha));
            u16 hb = f2bf(bb);
            pr[scol] = hb; pr[SEGI_ + scol] = f2bf(bb - bf2f(hb));
        }
    } else {
        // pad zeroing (kg==16, kl!=0): 240 threads cover 252 pad columns x 128 rows
        int t = chunk * 15 + kl - 1;        // 0..239
        for (int idx = t; idx < 252; idx += 240) {
            int col;
            u16* base;
            if (idx < 62)       { col = 258 + idx;                 base = ABe; }
            else if (idx < 124) { col = SEGI_ + 258 + (idx - 62);  base = ABe; }
            else if (idx < 188) { col = 256 + (idx - 124);         base = ABo; }
            else                { col = SEGI_ + 256 + (idx - 188); base = ABo; }
            for (int f = 0; f < NF_; ++f)
                base[(size_t)(b * NF_ + f) * PIRW_ + col] = 0;
        }
    }
}

// ---------------- conv2: sparse conv + inline OLA; hann via LDS LUT; NT stores --------
__global__ __launch_bounds__(256) void conv2_kernel(const float* __restrict__ E,
                                                    const float* __restrict__ O,
                                                    const int* __restrict__ cnt,
                                                    const float2* __restrict__ taps,
                                                    float* __restrict__ out) {
    // 256-entry cos LUT: one cosf per thread (same expression as before -> bit-identical)
    __shared__ float clut[256];
    clut[threadIdx.x] = cosf((float)threadIdx.x * (PI_ / 256.f));
    __syncthreads();
    int be = blockIdx.y;
    int b = be >> 4;
    int n = cnt[be];
    int t = blockIdx.x * 2048 + (int)threadIdx.x * 8;
    int r0 = t & 255;
    float hr[8], hr2[8];
    #pragma unroll
    for (int j = 0; j < 8; ++j) {
        float cj = clut[r0 + j];
        hr[j]  = 0.5f - 0.5f * cj;
        hr2[j] = 0.5f + 0.5f * cj;
    }
    float acc[8] = {};
    for (int i = 0; i < n; ++i) {
        float2 ka = taps[(size_t)be * NF_ + i];
        int s0 = t - ((int)ka.x << 8);
        if (s0 < 0) continue;
        float amp = ka.y;
        int q = s0 >> 8;
        size_t row = (size_t)(b * NF_ + q) * 256 + r0;
        float4 e0 = *(const float4*)(E + row);
        float4 e1 = *(const float4*)(E + row + 4);
        float4 o0 = *(const float4*)(O + row);
        float4 o1 = *(const float4*)(O + row + 4);
        float sv[8];
        sv[0] = hr[0] * (e0.x + o0.x); sv[1] = hr[1] * (e0.y + o0.y);
        sv[2] = hr[2] * (e0.z + o0.z); sv[3] = hr[3] * (e0.w + o0.w);
        sv[4] = hr[4] * (e1.x + o1.x); sv[5] = hr[5] * (e1.y + o1.y);
        sv[6] = hr[6] * (e1.z + o1.z); sv[7] = hr[7] * (e1.w + o1.w);
        if (q > 0) {
            float4 pe0 = *(const float4*)(E + row - 256);
            float4 pe1 = *(const float4*)(E + row - 252);
            float4 po0 = *(const float4*)(O + row - 256);
            float4 po1 = *(const float4*)(O + row - 252);
            sv[0] += hr2[0] * (pe0.x - po0.x); sv[1] += hr2[1] * (pe0.y - po0.y);
            sv[2] += hr2[2] * (pe0.z - po0.z); sv[3] += hr2[3] * (pe0.w - po0.w);
            sv[4] += hr2[4] * (pe1.x - po1.x); sv[5] += hr2[5] * (pe1.y - po1.y);
            sv[6] += hr2[6] * (pe1.z - po1.z); sv[7] += hr2[7] * (pe1.w - po1.w);
        }
        #pragma unroll
        for (int j = 0; j < 8; ++j) acc[j] += amp * sv[j];
    }
    float* op = out + (size_t)be * NS_ + t;
    f32x4 w0v = {acc[0], acc[1], acc[2], acc[3]};
    f32x4 w1v = {acc[4], acc[5], acc[6], acc[7]};
    __builtin_nontemporal_store(w0v, (f32x4*)op);
    __builtin_nontemporal_store(w1v, (f32x4*)(op + 4));
}

extern "C" void kernel_launch(void* const* d_in, const int* in_sizes, int n_in,
                              void* d_out, int out_size, void* d_ws, size_t ws_size,
                              hipStream_t stream) {
    const float* param  = (const float*)d_in[0];
    const float* times  = (const float*)d_in[1];
    const float* noise  = (const float*)d_in[2];
    const float* pos    = (const float*)d_in[3];
    const float* proj_w = (const float*)d_in[4];
    const float* proj_b = (const float*)d_in[5];
    const float* w0 = (const float*)d_in[6];
    const float* b0 = (const float*)d_in[7];
    const float* w1 = (const float*)d_in[8];
    const float* b1 = (const float*)d_in[9];
    const float* w2 = (const float*)d_in[10];
    const float* b2 = (const float*)d_in[11];
    const float* w_out = (const float*)d_in[12];
    const float* b_out = (const float*)d_in[13];
    float* out = (float*)d_out;
    float* ws = (float*)d_ws;

    // ws layout — cursor in FLOAT units; u16 buffers consume (u16_count/2) floats.
    constexpr size_t U_F    = 32 * 256;
    constexpr size_t V_F    = 128 * 256;
    constexpr size_t HP_F   = (size_t)ROWS_ * PMLW_ / 2;    // 1,048,576 per buffer
    constexpr size_t W_F    = (size_t)256 * PMLW_ / 2;      //    65,536
    constexpr size_t WO_F   = (size_t)576 * PMLW_ / 2;      //   147,456
    constexpr size_t RAW_F  = (size_t)ROWS_ * TC_;          // 2,105,344
    constexpr size_t ABP_F  = 2 * (size_t)ROWS_ * PIRW_ / 2;// 2,621,440
    constexpr size_t TTP_F  = 2 * (size_t)256 * PIRW_ / 2;  //   163,840
    constexpr size_t EO_F   = 2 * (size_t)ROWS_ * 256;      // 2,097,152

    size_t cur = 0;
    float* U    = ws + cur;                 cur += U_F;
    float* V    = ws + cur;                 cur += V_F;
    u16*  H1p   = (u16*)(ws + cur);         cur += HP_F;
    u16*  H2p   = (u16*)(ws + cur);         cur += HP_F;
    u16*  H3p   = (u16*)(ws + cur);         cur += HP_F;
    u16*  W1p   = (u16*)(ws + cur);         cur += W_F;
    u16*  W2p   = (u16*)(ws + cur);         cur += W_F;
    u16*  WOp   = (u16*)(ws + cur);         cur += WO_F;
    float* RAW  = ws + cur;                 cur += RAW_F;
    u16*  ABP   = (u16*)(ws + cur);         cur += ABP_F;
    u16*  ABe   = ABP;
    u16*  ABo   = ABP + (size_t)ROWS_ * PIRW_;
    u16*  TTP   = (u16*)(ws + cur);         cur += TTP_F;
    float* EO   = ws + cur;                 cur += EO_F;
    int*   CNT  = (int*)(ws + cur);         cur += 512;
    float2* TAPS = (float2*)(ws + cur);     // 512*128 float2

    // 1) fused prep: pair table (LUT) + weight pairs + taps + U + V
    prep_kernel<<<3040, 256, 0, stream>>>(param, proj_w, proj_b, pos, w0, w1, w2, w_out,
                                          times, TTP, W1p, W2p, WOp, CNT, TAPS, U, V);
    // 2) fuse1: H1 pair = lrelu(U[b]+V[f]+b0)
    fuse1_kernel<<<ROWS_ * CH_ / 256, 256, 0, stream>>>(U, V, b0, H1p);
    // 3) MLP layers 2,3 (bf16-split MFMA on pair buffers)
    mfgemm<0, K3MLP_, SEGM_><<<dim3(4, 128, 1), 128, 0, stream>>>(H1p, W1p, b1, H2p, 256,
                                                                  PMLW_, PMLW_, PMLW_, 0, 0, 0);
    mfgemm<0, K3MLP_, SEGM_><<<dim3(4, 128, 1), 128, 0, stream>>>(H2p, W2p, b2, H3p, 256,
                                                                  PMLW_, PMLW_, PMLW_, 0, 0, 0);
    // 4) output layer -> RAW fp32 (bias, N=514 guarded)
    mfgemm<1, K3MLP_, SEGM_><<<dim3(9, 128, 1), 128, 0, stream>>>(H3p, WOp, b_out, RAW, TC_,
                                                                  PMLW_, PMLW_, TC_, 0, 0, 0);
    // 5) fused phase scan (chunk sums in regs, serial LDS prefix, pads inline)
    scanf_kernel<<<dim3(B_, 17), 256, 0, stream>>>(RAW, noise, ABe, ABo);
    // 6) parity irfft (z-batched): EO[z] = AB[z] @ Tt[z]^T
    mfgemm<2, K3IR_, SEGI_><<<dim3(4, 128, 2), 128, 0, stream>>>(ABP, TTP, nullptr, EO, 256,
                                                                 PIRW_, PIRW_, 256,
                                                                 (size_t)ROWS_ * PIRW_,
                                                                 (size_t)256 * PIRW_,
                                                                 (size_t)ROWS_ * 256);
    // 7) sparse conv + inline OLA (hann LUT) -> out (non-temporal stores)
    dim3 gC(NS_ / 2048, B_ * NE_);
    conv2_kernel<<<gC, 256, 0, stream>>>(EO, EO + (size_t)ROWS_ * 256, CNT, TAPS, out);
}